// Round 1
// baseline (646.144 us; speedup 1.0000x reference)
//
#include <hip/hip_runtime.h>
#include <hip/hip_fp16.h>

// Problem constants (hardcoded per reference): B=256, S=512, D=80, H=128, T=3
#define BB 256
#define SS 512
#define DD 80
#define HH 128
#define GG 512   // 4*H

typedef _Float16 h2_t __attribute__((ext_vector_type(2)));

union U32H2 { unsigned int u; h2_t h; unsigned short us[2]; };

static __device__ __forceinline__ h2_t u2h(unsigned int u) { U32H2 x; x.u = u; return x.h; }

static __device__ __forceinline__ unsigned int pk2(float a, float b) {
  unsigned int lo = (unsigned int)__half_as_ushort(__float2half(a));
  unsigned int hi = (unsigned int)__half_as_ushort(__float2half(b));
  return (hi << 16) | lo;
}

static __device__ __forceinline__ float fdot2(unsigned int a, unsigned int b, float c) {
#if __has_builtin(__builtin_amdgcn_fdot2)
  return __builtin_amdgcn_fdot2(u2h(a), u2h(b), c, false);
#else
  U32H2 ua, ub; ua.u = a; ub.u = b;
  return c + (float)ua.h[0] * (float)ub.h[0] + (float)ua.h[1] * (float)ub.h[1];
#endif
}

static __device__ __forceinline__ float fsig(float x) {
  return __fdividef(1.f, 1.f + __expf(-x));
}
static __device__ __forceinline__ float ftanh(float x) {
  x = fminf(fmaxf(x, -15.f), 15.f);
  float e = __expf(2.f * x);
  return __fdividef(e - 1.f, e + 1.f);
}

// ---------------------------------------------------------------------------
// Kernel 1: prep. Wc = W_ih @ W_in (fp16, [512][80]), Whh fp16 [512][128],
// bias_comb = W_ih@b_in + b_ih + b_hh (fp32 [512]).
// ---------------------------------------------------------------------------
__global__ __launch_bounds__(128) void prep_kernel(
    const float* __restrict__ W_in, const float* __restrict__ b_in,
    const float* __restrict__ W_ih, const float* __restrict__ b_ih,
    const float* __restrict__ W_hh, const float* __restrict__ b_hh,
    unsigned short* __restrict__ wc16, unsigned short* __restrict__ whh16,
    float* __restrict__ biasc)
{
  const int g = blockIdx.x;     // 0..511
  const int t = threadIdx.x;    // 0..127
  const float* wih = W_ih + g * 256;
  if (t < DD) {
    float s = 0.f;
    for (int e = 0; e < 256; ++e) s += wih[e] * W_in[e * DD + t];
    wc16[g * DD + t] = __half_as_ushort(__float2half(s));
  }
  whh16[g * HH + t] = __half_as_ushort(__float2half(W_hh[g * HH + t]));
  if (t == 0) {
    float s = 0.f;
    for (int e = 0; e < 256; ++e) s += wih[e] * b_in[e];
    biasc[g] = s + b_ih[g] + b_hh[g];
  }
}

// ---------------------------------------------------------------------------
// Kernel 2: gates_x = x @ Wc.T, fp32 acc over fp16 dot2, output fp16 in the
// scan's interleaved layout: gx[(b*64+sb)*512 + g] is a uint4 holding 8
// consecutive steps (s = sb*8 .. sb*8+7) for gate g.
// Tile: Mtile=64 (s within one b), Ntile=256, K=80. Block 256 threads,
// micro-tile 8(m) x 8(g split 2x4).
// ---------------------------------------------------------------------------
__global__ __launch_bounds__(256) void gemm_kernel(
    const float* __restrict__ x,
    const unsigned short* __restrict__ wc16,
    uint4* __restrict__ gx)
{
  __shared__ unsigned int Al[40][64];    // [k-pair][m] fp16x2
  __shared__ unsigned int Bl[40][256];   // [k-pair][g] fp16x2
  const int t  = threadIdx.x;
  const int mt = blockIdx.x;             // 0..2047 (m-tile of 64 rows)
  const int g0 = blockIdx.y * 256;       // 0 or 256

  {
    const int mm = t & 63, kq = t >> 6;  // kq in 0..3, 10 pairs each
    const float* xr = x + ((size_t)mt * 64 + mm) * DD + kq * 20;
    #pragma unroll
    for (int p = 0; p < 10; ++p)
      Al[kq * 10 + p][mm] = pk2(xr[2 * p], xr[2 * p + 1]);
  }
  {
    const unsigned int* wr = (const unsigned int*)wc16 + (size_t)(g0 + t) * 40;
    #pragma unroll
    for (int k = 0; k < 40; ++k) Bl[k][t] = wr[k];
  }
  __syncthreads();

  const int mb = (t >> 5) * 8;
  const int gb = (t & 31) * 4;
  float acc[8][8];
  #pragma unroll
  for (int i = 0; i < 8; ++i)
    #pragma unroll
    for (int j = 0; j < 8; ++j) acc[i][j] = 0.f;

  #pragma unroll 5
  for (int kk = 0; kk < 40; ++kk) {
    uint4 a0 = *(const uint4*)&Al[kk][mb];
    uint4 a1 = *(const uint4*)&Al[kk][mb + 4];
    uint4 b0 = *(const uint4*)&Bl[kk][gb];
    uint4 b1 = *(const uint4*)&Bl[kk][gb + 128];
    unsigned int aa[8] = {a0.x, a0.y, a0.z, a0.w, a1.x, a1.y, a1.z, a1.w};
    unsigned int bb[8] = {b0.x, b0.y, b0.z, b0.w, b1.x, b1.y, b1.z, b1.w};
    #pragma unroll
    for (int i = 0; i < 8; ++i)
      #pragma unroll
      for (int j = 0; j < 8; ++j)
        acc[i][j] = fdot2(aa[i], bb[j], acc[i][j]);
  }

  // store: row-block rb covers s = rb*8..rb*8+7 (thread's 8 m's), per g one uint4
  const size_t rb = (size_t)mt * 8 + (t >> 5);
  #pragma unroll
  for (int jj = 0; jj < 2; ++jj) {
    #pragma unroll
    for (int j = 0; j < 4; ++j) {
      const int jc = jj * 4 + j;
      uint4 o;
      o.x = pk2(acc[0][jc], acc[1][jc]);
      o.y = pk2(acc[2][jc], acc[3][jc]);
      o.z = pk2(acc[4][jc], acc[5][jc]);
      o.w = pk2(acc[6][jc], acc[7][jc]);
      gx[rb * 512 + (size_t)(g0 + jj * 128 + gb + j)] = o;
    }
  }
}

// ---------------------------------------------------------------------------
// Kernel 3: the scan. One workgroup per batch element (256 wgs, 512 threads).
// Thread g owns gate g; W_hh row g lives in 64 VGPRs (fp16x2). h is packed
// fp16x2 in LDS (64 dwords); each step every lane loads hpk[lane] once and
// the 128-length dot runs as 64x (v_readlane + v_dot2_f32_f16).
// ---------------------------------------------------------------------------
__global__ __launch_bounds__(512) void scan_kernel(
    const uint4* __restrict__ gx,     // [(b*64+sb)*512 + g]
    const uint4* __restrict__ whh,    // [512][16] uint4 (fp16 rows)
    const float* __restrict__ biasc,  // [512]
    const float* __restrict__ wtime,  // [3]
    __half* __restrict__ hout)        // [B][S][128] fp16
{
  __shared__ unsigned int hpk[64];    // h as fp16x2
  __shared__ float act[512];
  const int b = blockIdx.x;
  const int t = threadIdx.x;

  unsigned int w[64];
  {
    const uint4* wr = whh + (size_t)t * 16;
    #pragma unroll
    for (int i = 0; i < 16; ++i) {
      uint4 v = wr[i];
      w[4*i] = v.x; w[4*i+1] = v.y; w[4*i+2] = v.z; w[4*i+3] = v.w;
    }
  }
  const float bias = biasc[t];
  const float wt0 = wtime[0], wt1 = wtime[1], wt2 = wtime[2];
  if (t < 64) hpk[t] = 0u;
  float c = 0.f, hst0 = 0.f, hst1 = 0.f, cst0 = 0.f, cst1 = 0.f;
  int slot = 0;
  int s = 0;
  const uint4* gxp = gx + (size_t)b * 64 * 512 + t;
  __syncthreads();

  uint4 gxv = gxp[0];
  for (int sb = 0; sb < 64; ++sb) {
    uint4 gxn;
    if (sb < 63) gxn = gxp[(size_t)(sb + 1) * 512];
    unsigned int ga[4] = {gxv.x, gxv.y, gxv.z, gxv.w};
    #pragma unroll
    for (int i = 0; i < 8; ++i) {
      const unsigned int hreg = hpk[t & 63];
      U32H2 gu; gu.u = ga[i >> 1];
      const float gxi = (float)gu.h[i & 1];
      // 128-long dot: 4 independent chains for ILP
      float ac0 = bias + gxi, ac1 = 0.f, ac2 = 0.f, ac3 = 0.f;
      #pragma unroll
      for (int p = 0; p < 64; p += 4) {
        unsigned int h0 = (unsigned int)__builtin_amdgcn_readlane((int)hreg, p);
        unsigned int h1 = (unsigned int)__builtin_amdgcn_readlane((int)hreg, p + 1);
        unsigned int h2 = (unsigned int)__builtin_amdgcn_readlane((int)hreg, p + 2);
        unsigned int h3 = (unsigned int)__builtin_amdgcn_readlane((int)hreg, p + 3);
        ac0 = fdot2(w[p],     h0, ac0);
        ac1 = fdot2(w[p + 1], h1, ac1);
        ac2 = fdot2(w[p + 2], h2, ac2);
        ac3 = fdot2(w[p + 3], h3, ac3);
      }
      const float accv = (ac0 + ac1) + (ac2 + ac3);
      const float a = (t >= 256 && t < 384) ? ftanh(accv) : fsig(accv);
      act[t] = a;
      __syncthreads();
      if (t < 128) {
        const float ig = act[t], fg = act[t + 128], gg = act[t + 256], og = act[t + 384];
        c = fg * c + ig * gg;
        const float hn = og * ftanh(c);
        float hcur;
        if (slot == 2) {
          hcur = hst0 * wt0 + hst1 * wt1 + hn * wt2;
          c    = cst0 * wt0 + cst1 * wt1 + c  * wt2;
        } else {
          hcur = hn;
          if (slot == 0) { hst0 = hn; cst0 = c; }
          else           { hst1 = hn; cst1 = c; }
        }
        const __half hh = __float2half(hcur);
        ((__half*)hpk)[t] = hh;
        hout[((size_t)b * SS + s) * HH + t] = hh;
      }
      slot = (slot == 2) ? 0 : slot + 1;
      ++s;
      __syncthreads();
    }
    gxv = gxn;
  }
}

// ---------------------------------------------------------------------------
// Kernel 4: epilogue. logits = h @ W_br.T + b_br, then log_softmax over 4.
// One thread per (b,s) row.
// ---------------------------------------------------------------------------
__global__ __launch_bounds__(256) void out_kernel(
    const uint4* __restrict__ hout,   // [B*S][16] uint4 (fp16 rows)
    const float* __restrict__ Wbr, const float* __restrict__ bbr,
    float4* __restrict__ out)
{
  __shared__ unsigned int wb[4][64];
  __shared__ float bbs[4];
  const int t = threadIdx.x;
  {
    const int o = t >> 6, p = t & 63;
    wb[o][p] = pk2(Wbr[o * HH + 2 * p], Wbr[o * HH + 2 * p + 1]);
  }
  if (t < 4) bbs[t] = bbr[t];
  __syncthreads();

  const size_t row = (size_t)blockIdx.x * 256 + t;
  const uint4* hr = hout + row * 16;
  float a0 = bbs[0], a1 = bbs[1], a2 = bbs[2], a3 = bbs[3];
  #pragma unroll
  for (int q = 0; q < 16; ++q) {
    uint4 hv = hr[q];
    unsigned int hd[4] = {hv.x, hv.y, hv.z, hv.w};
    #pragma unroll
    for (int d = 0; d < 4; ++d) {
      const int p = q * 4 + d;
      a0 = fdot2(hd[d], wb[0][p], a0);
      a1 = fdot2(hd[d], wb[1][p], a1);
      a2 = fdot2(hd[d], wb[2][p], a2);
      a3 = fdot2(hd[d], wb[3][p], a3);
    }
  }
  const float m = fmaxf(fmaxf(a0, a1), fmaxf(a2, a3));
  const float e0 = __expf(a0 - m), e1 = __expf(a1 - m), e2 = __expf(a2 - m), e3 = __expf(a3 - m);
  const float lse = m + __logf(e0 + e1 + e2 + e3);
  out[row] = make_float4(a0 - lse, a1 - lse, a2 - lse, a3 - lse);
}

// ---------------------------------------------------------------------------
extern "C" void kernel_launch(void* const* d_in, const int* in_sizes, int n_in,
                              void* d_out, int out_size, void* d_ws, size_t ws_size,
                              hipStream_t stream) {
  const float* x     = (const float*)d_in[0];
  const float* W_in  = (const float*)d_in[1];
  const float* b_in  = (const float*)d_in[2];
  const float* W_ih  = (const float*)d_in[3];
  const float* b_ih  = (const float*)d_in[4];
  const float* W_hh  = (const float*)d_in[5];
  const float* b_hh  = (const float*)d_in[6];
  const float* wtime = (const float*)d_in[7];
  const float* W_br  = (const float*)d_in[8];
  const float* b_br  = (const float*)d_in[9];
  (void)in_sizes; (void)n_in; (void)out_size; (void)ws_size;

  char* ws = (char*)d_ws;
  // ws layout (bytes, all 256-aligned):
  //   wc16  @ 0         : 512*80*2   = 81920
  //   whh16 @ 81920     : 512*128*2  = 131072
  //   biasc @ 212992    : 512*4      = 2048
  //   hout  @ 215040    : 256*512*128*2 = 33554432
  //   gx    @ 33769472  : 256*64*512*16 = 134217728   (end = 167987200)
  unsigned short* wc16  = (unsigned short*)(ws + 0);
  unsigned short* whh16 = (unsigned short*)(ws + 81920);
  float*          biasc = (float*)(ws + 212992);
  __half*         hout  = (__half*)(ws + 215040);
  uint4*          gx    = (uint4*)(ws + 33769472);

  prep_kernel<<<512, 128, 0, stream>>>(W_in, b_in, W_ih, b_ih, W_hh, b_hh,
                                       wc16, whh16, biasc);
  gemm_kernel<<<dim3(2048, 2), 256, 0, stream>>>(x, wc16, gx);
  scan_kernel<<<256, 512, 0, stream>>>(gx, (const uint4*)whh16, biasc, wtime, hout);
  out_kernel<<<512, 256, 0, stream>>>((const uint4*)hout, W_br, b_br, (float4*)d_out);
}

// Round 2
// 609.255 us; speedup vs baseline: 1.0605x; 1.0605x over previous
//
#include <hip/hip_runtime.h>
#include <hip/hip_fp16.h>

// Problem constants (hardcoded per reference): B=256, S=512, D=80, H=128, T=3
#define BB 256
#define SS 512
#define DD 80
#define HH 128
#define GG 512   // 4*H

typedef _Float16 h2_t __attribute__((ext_vector_type(2)));

union U32H2 { unsigned int u; h2_t h; unsigned short us[2]; };

static __device__ __forceinline__ h2_t u2h(unsigned int u) { U32H2 x; x.u = u; return x.h; }

static __device__ __forceinline__ unsigned int pk2(float a, float b) {
  unsigned int lo = (unsigned int)__half_as_ushort(__float2half(a));
  unsigned int hi = (unsigned int)__half_as_ushort(__float2half(b));
  return (hi << 16) | lo;
}

static __device__ __forceinline__ float fdot2(unsigned int a, unsigned int b, float c) {
#if __has_builtin(__builtin_amdgcn_fdot2)
  return __builtin_amdgcn_fdot2(u2h(a), u2h(b), c, false);
#else
  U32H2 ua, ub; ua.u = a; ub.u = b;
  return c + (float)ua.h[0] * (float)ub.h[0] + (float)ua.h[1] * (float)ub.h[1];
#endif
}

static __device__ __forceinline__ float fsig(float x) {
  return __fdividef(1.f, 1.f + __expf(-x));
}

// ---------------------------------------------------------------------------
// Kernel 1: prep. Wc = W_ih @ W_in (fp16, [512][80]), Whh fp16 [512][128],
// bias_comb = W_ih@b_in + b_ih + b_hh (fp32 [512]).
// ---------------------------------------------------------------------------
__global__ __launch_bounds__(128) void prep_kernel(
    const float* __restrict__ W_in, const float* __restrict__ b_in,
    const float* __restrict__ W_ih, const float* __restrict__ b_ih,
    const float* __restrict__ W_hh, const float* __restrict__ b_hh,
    unsigned short* __restrict__ wc16, unsigned short* __restrict__ whh16,
    float* __restrict__ biasc)
{
  const int g = blockIdx.x;     // 0..511
  const int t = threadIdx.x;    // 0..127
  const float* wih = W_ih + g * 256;
  if (t < DD) {
    float s = 0.f;
    for (int e = 0; e < 256; ++e) s += wih[e] * W_in[e * DD + t];
    wc16[g * DD + t] = __half_as_ushort(__float2half(s));
  }
  whh16[g * HH + t] = __half_as_ushort(__float2half(W_hh[g * HH + t]));
  if (t == 0) {
    float s = 0.f;
    for (int e = 0; e < 256; ++e) s += wih[e] * b_in[e];
    biasc[g] = s + b_ih[g] + b_hh[g];
  }
}

// ---------------------------------------------------------------------------
// Kernel 2: gates_x = x @ Wc.T, fp32 acc over fp16 dot2, output fp16 in the
// scan's interleaved layout: gx[(b*64+sb)*512 + g] is a uint4 holding 8
// consecutive steps (s = sb*8 .. sb*8+7) for gate g.
// ---------------------------------------------------------------------------
__global__ __launch_bounds__(256) void gemm_kernel(
    const float* __restrict__ x,
    const unsigned short* __restrict__ wc16,
    uint4* __restrict__ gx)
{
  __shared__ unsigned int Al[40][64];    // [k-pair][m] fp16x2
  __shared__ unsigned int Bl[40][256];   // [k-pair][g] fp16x2
  const int t  = threadIdx.x;
  const int mt = blockIdx.x;             // 0..2047 (m-tile of 64 rows)
  const int g0 = blockIdx.y * 256;       // 0 or 256

  {
    const int mm = t & 63, kq = t >> 6;  // kq in 0..3, 10 pairs each
    const float* xr = x + ((size_t)mt * 64 + mm) * DD + kq * 20;
    #pragma unroll
    for (int p = 0; p < 10; ++p)
      Al[kq * 10 + p][mm] = pk2(xr[2 * p], xr[2 * p + 1]);
  }
  {
    const unsigned int* wr = (const unsigned int*)wc16 + (size_t)(g0 + t) * 40;
    #pragma unroll
    for (int k = 0; k < 40; ++k) Bl[k][t] = wr[k];
  }
  __syncthreads();

  const int mb = (t >> 5) * 8;
  const int gb = (t & 31) * 4;
  float acc[8][8];
  #pragma unroll
  for (int i = 0; i < 8; ++i)
    #pragma unroll
    for (int j = 0; j < 8; ++j) acc[i][j] = 0.f;

  #pragma unroll 5
  for (int kk = 0; kk < 40; ++kk) {
    uint4 a0 = *(const uint4*)&Al[kk][mb];
    uint4 a1 = *(const uint4*)&Al[kk][mb + 4];
    uint4 b0 = *(const uint4*)&Bl[kk][gb];
    uint4 b1 = *(const uint4*)&Bl[kk][gb + 128];
    unsigned int aa[8] = {a0.x, a0.y, a0.z, a0.w, a1.x, a1.y, a1.z, a1.w};
    unsigned int bb[8] = {b0.x, b0.y, b0.z, b0.w, b1.x, b1.y, b1.z, b1.w};
    #pragma unroll
    for (int i = 0; i < 8; ++i)
      #pragma unroll
      for (int j = 0; j < 8; ++j)
        acc[i][j] = fdot2(aa[i], bb[j], acc[i][j]);
  }

  const size_t rb = (size_t)mt * 8 + (t >> 5);
  #pragma unroll
  for (int jj = 0; jj < 2; ++jj) {
    #pragma unroll
    for (int j = 0; j < 4; ++j) {
      const int jc = jj * 4 + j;
      uint4 o;
      o.x = pk2(acc[0][jc], acc[1][jc]);
      o.y = pk2(acc[2][jc], acc[3][jc]);
      o.z = pk2(acc[4][jc], acc[5][jc]);
      o.w = pk2(acc[6][jc], acc[7][jc]);
      gx[rb * 512 + (size_t)(g0 + jj * 128 + gb + j)] = o;
    }
  }
}

// ---------------------------------------------------------------------------
// Kernel 3: the scan, v2. One workgroup per batch chain (256 wgs, 256 thr).
// Thread t owns TWO gate rows: g1 = (t&1)*128 + (t>>1)  (i-gate on even
// lanes, f-gate on odd), g2 = g1 + 256 (g-gate / o-gate). Both W_hh rows
// (128 fp16x2 dwords) live in VGPRs — __launch_bounds__(256,1) lifts the
// VGPR cap to ~512 so the allocator keeps them (R1's VGPR=48 reload bug).
// h broadcast: one ds_read of hbuf[par][lane], then 64 v_readlane shared by
// BOTH gates' v_dot2 chains. Activation exchange between the (even,odd)
// lane pair via __shfl_xor(.,1) — intra-wave, no barrier. hbuf is
// double-buffered so each step needs only ONE __syncthreads.
// ---------------------------------------------------------------------------
__global__ __launch_bounds__(256, 1) void scan_kernel(
    const uint4* __restrict__ gx,     // [(b*64+sb)*512 + g]
    const uint4* __restrict__ whh,    // [512][16] uint4 (fp16 rows)
    const float* __restrict__ biasc,  // [512]
    const float* __restrict__ wtime,  // [3]
    __half* __restrict__ hout)        // [B][S][128] fp16
{
  __shared__ unsigned int hbuf[2][64];  // h as fp16x2, double-buffered
  const int b    = blockIdx.x;
  const int t    = threadIdx.x;         // 0..255
  const int lane = t & 63;
  const int hi   = t >> 1;              // 0..127
  const int odd  = t & 1;
  const int g1   = odd * 128 + hi;      // i (even) / f (odd)
  const int g2   = g1 + 256;            // g (even) / o (odd)

  unsigned int w1[64], w2[64];
  {
    const uint4* wr1 = whh + (size_t)g1 * 16;
    const uint4* wr2 = whh + (size_t)g2 * 16;
    #pragma unroll
    for (int i = 0; i < 16; ++i) {
      uint4 v = wr1[i];
      w1[4*i] = v.x; w1[4*i+1] = v.y; w1[4*i+2] = v.z; w1[4*i+3] = v.w;
      uint4 u = wr2[i];
      w2[4*i] = u.x; w2[4*i+1] = u.y; w2[4*i+2] = u.z; w2[4*i+3] = u.w;
    }
  }
  const float bias1 = biasc[g1];
  const float bias2 = biasc[g2];
  const float wt0 = wtime[0], wt1 = wtime[1], wt2 = wtime[2];
  if (t < 64) { hbuf[0][t] = 0u; hbuf[1][t] = 0u; }
  float c = 0.f, hst0 = 0.f, hst1 = 0.f, cst0 = 0.f, cst1 = 0.f;
  int slot = 0, s = 0;
  const uint4* gxp1 = gx + (size_t)b * 64 * 512 + g1;
  const uint4* gxp2 = gx + (size_t)b * 64 * 512 + g2;
  __syncthreads();

  uint4 gv1 = gxp1[0];
  uint4 gv2 = gxp2[0];
  for (int sb = 0; sb < 64; ++sb) {
    uint4 gn1, gn2;
    if (sb < 63) {
      gn1 = gxp1[(size_t)(sb + 1) * 512];
      gn2 = gxp2[(size_t)(sb + 1) * 512];
    }
    unsigned int ga1[4] = {gv1.x, gv1.y, gv1.z, gv1.w};
    unsigned int ga2[4] = {gv2.x, gv2.y, gv2.z, gv2.w};
    #pragma unroll
    for (int i = 0; i < 8; ++i) {
      const int par = s & 1;
      const unsigned int hreg = hbuf[par][lane];
      U32H2 u1; u1.u = ga1[i >> 1];
      U32H2 u2; u2.u = ga2[i >> 1];
      const float gxi1 = (float)u1.h[i & 1];
      const float gxi2 = (float)u2.h[i & 1];
      float d1a = bias1 + gxi1, d1b = 0.f;
      float d2a = bias2 + gxi2, d2b = 0.f;
      #pragma unroll
      for (int p = 0; p < 64; p += 2) {
        unsigned int h0 = (unsigned int)__builtin_amdgcn_readlane((int)hreg, p);
        unsigned int h1 = (unsigned int)__builtin_amdgcn_readlane((int)hreg, p + 1);
        d1a = fdot2(w1[p],     h0, d1a);
        d2a = fdot2(w2[p],     h0, d2a);
        d1b = fdot2(w1[p + 1], h1, d1b);
        d2b = fdot2(w2[p + 1], h1, d2b);
      }
      const float d1 = d1a + d1b;
      const float d2 = d2a + d2b;
      // a1: sigmoid for both parities (i-gate even / f-gate odd)
      const float a1 = fsig(d1);
      // a2: tanh on even (g-gate), sigmoid on odd (o-gate):
      //   tanh(x) = 2*sigmoid(2x)-1 — share the sigmoid hardware path
      const float yin = odd ? d2 : (d2 + d2);
      const float sv  = fsig(yin);
      const float a2  = odd ? sv : (2.f * sv - 1.f);
      // pair exchange (even lane 2k <-> odd lane 2k+1), intra-wave
      const float p1 = __shfl_xor(a1, 1);
      const float p2 = __shfl_xor(a2, 1);
      const float iv = odd ? p1 : a1;
      const float gg = odd ? p2 : a2;
      const float fv = odd ? a1 : p1;
      const float ov = odd ? a2 : p2;
      c = fv * c + iv * gg;
      const float tc = 2.f * fsig(c + c) - 1.f;   // tanh(c)
      const float hn = ov * tc;
      float hcur;
      if (slot == 2) {
        hcur = hst0 * wt0 + hst1 * wt1 + hn * wt2;
        c    = cst0 * wt0 + cst1 * wt1 + c  * wt2;
        slot = 0;
      } else {
        hcur = hn;
        if (slot == 0) { hst0 = hn; cst0 = c; }
        else           { hst1 = hn; cst1 = c; }
        ++slot;
      }
      if (!odd) {
        const __half hh = __float2half(hcur);
        ((__half*)hbuf[par ^ 1])[hi] = hh;
        hout[((size_t)b * SS + s) * HH + hi] = hh;
      }
      ++s;
      __syncthreads();
    }
    gv1 = gn1;
    gv2 = gn2;
  }
}

// ---------------------------------------------------------------------------
// Kernel 4: epilogue. logits = h @ W_br.T + b_br, then log_softmax over 4.
// One thread per (b,s) row.
// ---------------------------------------------------------------------------
__global__ __launch_bounds__(256) void out_kernel(
    const uint4* __restrict__ hout,   // [B*S][16] uint4 (fp16 rows)
    const float* __restrict__ Wbr, const float* __restrict__ bbr,
    float4* __restrict__ out)
{
  __shared__ unsigned int wb[4][64];
  __shared__ float bbs[4];
  const int t = threadIdx.x;
  {
    const int o = t >> 6, p = t & 63;
    wb[o][p] = pk2(Wbr[o * HH + 2 * p], Wbr[o * HH + 2 * p + 1]);
  }
  if (t < 4) bbs[t] = bbr[t];
  __syncthreads();

  const size_t row = (size_t)blockIdx.x * 256 + t;
  const uint4* hr = hout + row * 16;
  float a0 = bbs[0], a1 = bbs[1], a2 = bbs[2], a3 = bbs[3];
  #pragma unroll
  for (int q = 0; q < 16; ++q) {
    uint4 hv = hr[q];
    unsigned int hd[4] = {hv.x, hv.y, hv.z, hv.w};
    #pragma unroll
    for (int d = 0; d < 4; ++d) {
      const int p = q * 4 + d;
      a0 = fdot2(hd[d], wb[0][p], a0);
      a1 = fdot2(hd[d], wb[1][p], a1);
      a2 = fdot2(hd[d], wb[2][p], a2);
      a3 = fdot2(hd[d], wb[3][p], a3);
    }
  }
  const float m = fmaxf(fmaxf(a0, a1), fmaxf(a2, a3));
  const float e0 = __expf(a0 - m), e1 = __expf(a1 - m), e2 = __expf(a2 - m), e3 = __expf(a3 - m);
  const float lse = m + __logf(e0 + e1 + e2 + e3);
  out[row] = make_float4(a0 - lse, a1 - lse, a2 - lse, a3 - lse);
}

// ---------------------------------------------------------------------------
extern "C" void kernel_launch(void* const* d_in, const int* in_sizes, int n_in,
                              void* d_out, int out_size, void* d_ws, size_t ws_size,
                              hipStream_t stream) {
  const float* x     = (const float*)d_in[0];
  const float* W_in  = (const float*)d_in[1];
  const float* b_in  = (const float*)d_in[2];
  const float* W_ih  = (const float*)d_in[3];
  const float* b_ih  = (const float*)d_in[4];
  const float* W_hh  = (const float*)d_in[5];
  const float* b_hh  = (const float*)d_in[6];
  const float* wtime = (const float*)d_in[7];
  const float* W_br  = (const float*)d_in[8];
  const float* b_br  = (const float*)d_in[9];
  (void)in_sizes; (void)n_in; (void)out_size; (void)ws_size;

  char* ws = (char*)d_ws;
  // ws layout (bytes, all 256-aligned):
  //   wc16  @ 0         : 512*80*2   = 81920
  //   whh16 @ 81920     : 512*128*2  = 131072
  //   biasc @ 212992    : 512*4      = 2048
  //   hout  @ 215040    : 256*512*128*2 = 33554432
  //   gx    @ 33769472  : 256*64*512*16 = 134217728   (end = 167987200)
  unsigned short* wc16  = (unsigned short*)(ws + 0);
  unsigned short* whh16 = (unsigned short*)(ws + 81920);
  float*          biasc = (float*)(ws + 212992);
  __half*         hout  = (__half*)(ws + 215040);
  uint4*          gx    = (uint4*)(ws + 33769472);

  prep_kernel<<<512, 128, 0, stream>>>(W_in, b_in, W_ih, b_ih, W_hh, b_hh,
                                       wc16, whh16, biasc);
  gemm_kernel<<<dim3(2048, 2), 256, 0, stream>>>(x, wc16, gx);
  scan_kernel<<<256, 256, 0, stream>>>(gx, (const uint4*)whh16, biasc, wtime, hout);
  out_kernel<<<512, 256, 0, stream>>>((const uint4*)hout, W_br, b_br, (float4*)d_out);
}

// Round 3
// 559.864 us; speedup vs baseline: 1.1541x; 1.0882x over previous
//
#include <hip/hip_runtime.h>
#include <hip/hip_fp16.h>

// Problem constants (hardcoded per reference): B=256, S=512, D=80, H=128, T=3
#define BB 256
#define SS 512
#define DD 80
#define HH 128
#define GG 512   // 4*H

typedef _Float16 h2_t __attribute__((ext_vector_type(2)));
typedef _Float16 half8 __attribute__((ext_vector_type(8)));
typedef float f32x4 __attribute__((ext_vector_type(4)));

union U32H2 { unsigned int u; h2_t h; unsigned short us[2]; };

static __device__ __forceinline__ h2_t u2h(unsigned int u) { U32H2 x; x.u = u; return x.h; }

static __device__ __forceinline__ unsigned int pk2(float a, float b) {
  unsigned int lo = (unsigned int)__half_as_ushort(__float2half(a));
  unsigned int hi = (unsigned int)__half_as_ushort(__float2half(b));
  return (hi << 16) | lo;
}

static __device__ __forceinline__ float fdot2(unsigned int a, unsigned int b, float c) {
#if __has_builtin(__builtin_amdgcn_fdot2)
  return __builtin_amdgcn_fdot2(u2h(a), u2h(b), c, false);
#else
  U32H2 ua, ub; ua.u = a; ub.u = b;
  return c + (float)ua.h[0] * (float)ub.h[0] + (float)ua.h[1] * (float)ub.h[1];
#endif
}

static __device__ __forceinline__ float fsig(float x) {
  return __fdividef(1.f, 1.f + __expf(-x));
}

// ---------------------------------------------------------------------------
// Kernel 1: prep. Wc = W_ih @ W_in (fp16, [512][80]), Whh fp16 [512][128],
// bias_comb = W_ih@b_in + b_ih + b_hh (fp32 [512]).
// ---------------------------------------------------------------------------
__global__ __launch_bounds__(128) void prep_kernel(
    const float* __restrict__ W_in, const float* __restrict__ b_in,
    const float* __restrict__ W_ih, const float* __restrict__ b_ih,
    const float* __restrict__ W_hh, const float* __restrict__ b_hh,
    unsigned short* __restrict__ wc16, unsigned short* __restrict__ whh16,
    float* __restrict__ biasc)
{
  const int g = blockIdx.x;     // 0..511
  const int t = threadIdx.x;    // 0..127
  const float* wih = W_ih + g * 256;
  if (t < DD) {
    float s = 0.f;
    for (int e = 0; e < 256; ++e) s += wih[e] * W_in[e * DD + t];
    wc16[g * DD + t] = __half_as_ushort(__float2half(s));
  }
  whh16[g * HH + t] = __half_as_ushort(__float2half(W_hh[g * HH + t]));
  if (t == 0) {
    float s = 0.f;
    for (int e = 0; e < 256; ++e) s += wih[e] * b_in[e];
    biasc[g] = s + b_ih[g] + b_hh[g];
  }
}

// ---------------------------------------------------------------------------
// Kernel 2 (v2, MFMA): gates_x = x @ Wc.T via v_mfma_f32_16x16x32_f16,
// K=80 zero-padded to 96 inside LDS (3 k-steps of 32). The old dot2 version
// was VALU-bound at >=137us (10.7 GFLOP / 78 TF dot2 ceiling); MFMA makes
// this HBM-bound (~28us: 42MB x read + 134MB gx write).
// Block: 256 thr, tile M=64 (rows of one b), N=128 gates. Grid (2048, 4).
// LDS pitch 52 dwords (208B): 16B-aligned for ds_read_b128, m*52 mod 32 has
// period 8 -> 2-way bank aliasing only (free per m136).
// Output stays in the scan's layout: gx[(mt*8+sb)*512+g] = uint4 of 8
// consecutive steps for gate g (D-frag rows q*4..q*4+3 + shfl_down(16) from
// the q+1 partner lane).
// ---------------------------------------------------------------------------
__global__ __launch_bounds__(256) void gemm_kernel(
    const float* __restrict__ x,
    const unsigned int* __restrict__ wc,   // [512][40] dwords (fp16x2)
    uint4* __restrict__ gx)
{
  __shared__ unsigned int Al[64 * 52];
  __shared__ unsigned int Bl[128 * 52];
  const int t  = threadIdx.x;
  const int mt = blockIdx.x;             // 0..2047 (m-tile of 64 rows)
  const int g0 = blockIdx.y * 128;       // gate tile base

  // stage A: 64 rows x 80 fp32 -> fp16x2, pad dwords 40..51 with 0
  {
    const float4* xr = (const float4*)(x + (size_t)mt * 64 * DD);
    #pragma unroll
    for (int i = 0; i < 5; ++i) {
      int f = t + i * 256;               // < 1280
      int row = f / 20, c4 = f % 20;
      float4 v = xr[row * 20 + c4];
      Al[row * 52 + c4 * 2]     = pk2(v.x, v.y);
      Al[row * 52 + c4 * 2 + 1] = pk2(v.z, v.w);
    }
    #pragma unroll
    for (int i = 0; i < 3; ++i) {
      int f = t + i * 256;               // < 768
      int row = f / 12, c = f % 12;
      Al[row * 52 + 40 + c] = 0u;
    }
  }
  // stage B: Wc rows g0..g0+127 (40 dwords each), pad dwords 40..51 with 0
  {
    #pragma unroll
    for (int i = 0; i < 5; ++i) {
      int f = t + i * 256;               // < 1280 uint4
      int row = f / 10, c4 = f % 10;
      uint4 v = *(const uint4*)(wc + (size_t)(g0 + row) * 40 + c4 * 4);
      *(uint4*)&Bl[row * 52 + c4 * 4] = v;
    }
    #pragma unroll
    for (int i = 0; i < 3; ++i) {
      int f = t + i * 256;               // < 768
      int row = f / 12, c = f % 12;
      Bl[row * 52 + 40 + c] = 0u;
    }
  }
  __syncthreads();

  const int w = t >> 6, lane = t & 63;
  const int m = lane & 15, q = lane >> 4;

  // A-frag: A[mrow = w*16+m][k = kk*32 + q*8 + j], 16B contiguous
  half8 af[3];
  #pragma unroll
  for (int kk = 0; kk < 3; ++kk)
    af[kk] = *(const half8*)((const char*)Al + (size_t)(w * 16 + m) * 208 + kk * 64 + q * 16);

  #pragma unroll
  for (int j = 0; j < 8; ++j) {
    f32x4 acc = {0.f, 0.f, 0.f, 0.f};
    #pragma unroll
    for (int kk = 0; kk < 3; ++kk) {
      // B-frag: B[k][n] with n = g0+j*16+m  <=>  Wc_lds[j*16+m][k]
      half8 bf = *(const half8*)((const char*)Bl + (size_t)(j * 16 + m) * 208 + kk * 64 + q * 16);
      acc = __builtin_amdgcn_mfma_f32_16x16x32_f16(af[kk], bf, acc, 0, 0, 0);
    }
    // D layout: row mrow = w*16 + q*4 + r, col = j*16 + m
    unsigned int lo  = pk2(acc[0], acc[1]);       // s offsets q*4+0, q*4+1
    unsigned int hi  = pk2(acc[2], acc[3]);       // s offsets q*4+2, q*4+3
    unsigned int plo = (unsigned int)__shfl_down((int)lo, 16);
    unsigned int phi = (unsigned int)__shfl_down((int)hi, 16);
    if ((q & 1) == 0) {
      uint4 o; o.x = lo; o.y = hi; o.z = plo; o.w = phi;
      gx[((size_t)mt * 8 + w * 2 + (q >> 1)) * 512 + (size_t)(g0 + j * 16 + m)] = o;
    }
  }
}

// ---------------------------------------------------------------------------
// Kernel 3: the scan. One workgroup per batch chain (256 wgs, 256 thr).
// Thread t owns TWO gate rows: g1 = (t&1)*128 + (t>>1) (i even / f odd),
// g2 = g1 + 256 (g even / o odd). Both W_hh rows (128 fp16x2 dwords) must
// stay in VGPRs. R2 lesson: __launch_bounds__(256,1) only sets the MIN
// waves/EU; the scheduler still targeted 6 waves/EU -> VGPR=84 -> weights
// reloaded from L2 every step (428us, matches 128KB/CU/step at ~56B/cy).
// amdgpu_waves_per_eu(1,1) caps the MAX, which is what clamps the
// scheduler's occupancy target -> 512-VGPR budget. 1 wave/EU == our actual
// occupancy (4-wave block, 1 block/CU), so no HW downside.
// ---------------------------------------------------------------------------
__global__ __attribute__((amdgpu_waves_per_eu(1, 1))) __launch_bounds__(256)
void scan_kernel(
    const uint4* __restrict__ gx,     // [(b*64+sb)*512 + g]
    const uint4* __restrict__ whh,    // [512][16] uint4 (fp16 rows)
    const float* __restrict__ biasc,  // [512]
    const float* __restrict__ wtime,  // [3]
    __half* __restrict__ hout)        // [B][S][128] fp16
{
  __shared__ unsigned int hbuf[2][64];  // h as fp16x2, double-buffered
  const int b    = blockIdx.x;
  const int t    = threadIdx.x;         // 0..255
  const int lane = t & 63;
  const int hi   = t >> 1;              // 0..127
  const int odd  = t & 1;
  const int g1   = odd * 128 + hi;      // i (even) / f (odd)
  const int g2   = g1 + 256;            // g (even) / o (odd)

  unsigned int w1[64], w2[64];
  {
    const uint4* wr1 = whh + (size_t)g1 * 16;
    const uint4* wr2 = whh + (size_t)g2 * 16;
    #pragma unroll
    for (int i = 0; i < 16; ++i) {
      uint4 v = wr1[i];
      w1[4*i] = v.x; w1[4*i+1] = v.y; w1[4*i+2] = v.z; w1[4*i+3] = v.w;
      uint4 u = wr2[i];
      w2[4*i] = u.x; w2[4*i+1] = u.y; w2[4*i+2] = u.z; w2[4*i+3] = u.w;
    }
  }
  const float bias1 = biasc[g1];
  const float bias2 = biasc[g2];
  const float wt0 = wtime[0], wt1 = wtime[1], wt2 = wtime[2];
  if (t < 64) { hbuf[0][t] = 0u; hbuf[1][t] = 0u; }
  float c = 0.f, hst0 = 0.f, hst1 = 0.f, cst0 = 0.f, cst1 = 0.f;
  int slot = 0, s = 0;
  const uint4* gxp1 = gx + (size_t)b * 64 * 512 + g1;
  const uint4* gxp2 = gx + (size_t)b * 64 * 512 + g2;
  __syncthreads();

  uint4 gv1 = gxp1[0];
  uint4 gv2 = gxp2[0];
  for (int sb = 0; sb < 64; ++sb) {
    uint4 gn1, gn2;
    if (sb < 63) {
      gn1 = gxp1[(size_t)(sb + 1) * 512];
      gn2 = gxp2[(size_t)(sb + 1) * 512];
    }
    unsigned int ga1[4] = {gv1.x, gv1.y, gv1.z, gv1.w};
    unsigned int ga2[4] = {gv2.x, gv2.y, gv2.z, gv2.w};
    #pragma unroll
    for (int i = 0; i < 8; ++i) {
      const int par = s & 1;
      const unsigned int hreg = hbuf[par][lane];
      U32H2 u1; u1.u = ga1[i >> 1];
      U32H2 u2; u2.u = ga2[i >> 1];
      const float gxi1 = (float)u1.h[i & 1];
      const float gxi2 = (float)u2.h[i & 1];
      float d1a = bias1 + gxi1, d1b = 0.f;
      float d2a = bias2 + gxi2, d2b = 0.f;
      #pragma unroll
      for (int p = 0; p < 64; p += 2) {
        unsigned int h0 = (unsigned int)__builtin_amdgcn_readlane((int)hreg, p);
        unsigned int h1 = (unsigned int)__builtin_amdgcn_readlane((int)hreg, p + 1);
        d1a = fdot2(w1[p],     h0, d1a);
        d2a = fdot2(w2[p],     h0, d2a);
        d1b = fdot2(w1[p + 1], h1, d1b);
        d2b = fdot2(w2[p + 1], h1, d2b);
      }
      const float d1 = d1a + d1b;
      const float d2 = d2a + d2b;
      // a1: sigmoid both parities (i even / f odd)
      const float a1 = fsig(d1);
      // a2: tanh on even (g-gate) via 2*sigmoid(2x)-1, sigmoid on odd (o)
      const float yin = odd ? d2 : (d2 + d2);
      const float sv  = fsig(yin);
      const float a2  = odd ? sv : (2.f * sv - 1.f);
      // pair exchange (even lane 2k <-> odd lane 2k+1), intra-wave
      const float p1 = __shfl_xor(a1, 1);
      const float p2 = __shfl_xor(a2, 1);
      const float iv = odd ? p1 : a1;
      const float gg = odd ? p2 : a2;
      const float fv = odd ? a1 : p1;
      const float ov = odd ? a2 : p2;
      c = fv * c + iv * gg;
      const float tc = 2.f * fsig(c + c) - 1.f;   // tanh(c)
      const float hn = ov * tc;
      float hcur;
      if (slot == 2) {
        hcur = hst0 * wt0 + hst1 * wt1 + hn * wt2;
        c    = cst0 * wt0 + cst1 * wt1 + c  * wt2;
        slot = 0;
      } else {
        hcur = hn;
        if (slot == 0) { hst0 = hn; cst0 = c; }
        else           { hst1 = hn; cst1 = c; }
        ++slot;
      }
      if (!odd) {
        const __half hh = __float2half(hcur);
        ((__half*)hbuf[par ^ 1])[hi] = hh;
        hout[((size_t)b * SS + s) * HH + hi] = hh;
      }
      ++s;
      __syncthreads();
    }
    gv1 = gn1;
    gv2 = gn2;
  }
}

// ---------------------------------------------------------------------------
// Kernel 4: epilogue. logits = h @ W_br.T + b_br, then log_softmax over 4.
// One thread per (b,s) row.
// ---------------------------------------------------------------------------
__global__ __launch_bounds__(256) void out_kernel(
    const uint4* __restrict__ hout,   // [B*S][16] uint4 (fp16 rows)
    const float* __restrict__ Wbr, const float* __restrict__ bbr,
    float4* __restrict__ out)
{
  __shared__ unsigned int wb[4][64];
  __shared__ float bbs[4];
  const int t = threadIdx.x;
  {
    const int o = t >> 6, p = t & 63;
    wb[o][p] = pk2(Wbr[o * HH + 2 * p], Wbr[o * HH + 2 * p + 1]);
  }
  if (t < 4) bbs[t] = bbr[t];
  __syncthreads();

  const size_t row = (size_t)blockIdx.x * 256 + t;
  const uint4* hr = hout + row * 16;
  float a0 = bbs[0], a1 = bbs[1], a2 = bbs[2], a3 = bbs[3];
  #pragma unroll
  for (int q = 0; q < 16; ++q) {
    uint4 hv = hr[q];
    unsigned int hd[4] = {hv.x, hv.y, hv.z, hv.w};
    #pragma unroll
    for (int d = 0; d < 4; ++d) {
      const int p = q * 4 + d;
      a0 = fdot2(hd[d], wb[0][p], a0);
      a1 = fdot2(hd[d], wb[1][p], a1);
      a2 = fdot2(hd[d], wb[2][p], a2);
      a3 = fdot2(hd[d], wb[3][p], a3);
    }
  }
  const float m = fmaxf(fmaxf(a0, a1), fmaxf(a2, a3));
  const float e0 = __expf(a0 - m), e1 = __expf(a1 - m), e2 = __expf(a2 - m), e3 = __expf(a3 - m);
  const float lse = m + __logf(e0 + e1 + e2 + e3);
  out[row] = make_float4(a0 - lse, a1 - lse, a2 - lse, a3 - lse);
}

// ---------------------------------------------------------------------------
extern "C" void kernel_launch(void* const* d_in, const int* in_sizes, int n_in,
                              void* d_out, int out_size, void* d_ws, size_t ws_size,
                              hipStream_t stream) {
  const float* x     = (const float*)d_in[0];
  const float* W_in  = (const float*)d_in[1];
  const float* b_in  = (const float*)d_in[2];
  const float* W_ih  = (const float*)d_in[3];
  const float* b_ih  = (const float*)d_in[4];
  const float* W_hh  = (const float*)d_in[5];
  const float* b_hh  = (const float*)d_in[6];
  const float* wtime = (const float*)d_in[7];
  const float* W_br  = (const float*)d_in[8];
  const float* b_br  = (const float*)d_in[9];
  (void)in_sizes; (void)n_in; (void)out_size; (void)ws_size;

  char* ws = (char*)d_ws;
  // ws layout (bytes, all 256-aligned):
  //   wc16  @ 0         : 512*80*2   = 81920
  //   whh16 @ 81920     : 512*128*2  = 131072
  //   biasc @ 212992    : 512*4      = 2048
  //   hout  @ 215040    : 256*512*128*2 = 33554432
  //   gx    @ 33769472  : 256*64*512*16 = 134217728   (end = 167987200)
  unsigned short* wc16  = (unsigned short*)(ws + 0);
  unsigned short* whh16 = (unsigned short*)(ws + 81920);
  float*          biasc = (float*)(ws + 212992);
  __half*         hout  = (__half*)(ws + 215040);
  uint4*          gx    = (uint4*)(ws + 33769472);

  prep_kernel<<<512, 128, 0, stream>>>(W_in, b_in, W_ih, b_ih, W_hh, b_hh,
                                       wc16, whh16, biasc);
  gemm_kernel<<<dim3(2048, 4), 256, 0, stream>>>(x, (const unsigned int*)wc16, gx);
  scan_kernel<<<256, 256, 0, stream>>>(gx, (const uint4*)whh16, biasc, wtime, hout);
  out_kernel<<<512, 256, 0, stream>>>((const uint4*)hout, W_br, b_br, (float4*)d_out);
}